// Round 1
// baseline (315.569 us; speedup 1.0000x reference)
//
#include <hip/hip_runtime.h>

typedef __attribute__((ext_vector_type(8))) short bf16x8;
typedef __attribute__((ext_vector_type(4))) float f32x4;

#define DEVI static __device__ __forceinline__

DEVI unsigned short f2bf(float f) {
  unsigned u = __builtin_bit_cast(unsigned, f);
  return (unsigned short)((u + 0x7FFFu + ((u >> 16) & 1u)) >> 16);
}

DEVI float fast_exp2(float x) {
#if __has_builtin(__builtin_amdgcn_exp2f)
  return __builtin_amdgcn_exp2f(x);
#else
  return exp2f(x);
#endif
}

// ---------------------------------------------------------------------------
// Transpose fp32 src[K][srcN] (column window col0..col0+320) -> bf16 dst[320][K]
// ---------------------------------------------------------------------------
__global__ __launch_bounds__(256)
void k_transpose(const float* __restrict__ src, int srcK, int srcN, int col0,
                 unsigned short* __restrict__ dst) {
  __shared__ float tile[32][33];
  const int k0 = blockIdx.x * 32;
  const int n0 = blockIdx.y * 32;
  const int tx = threadIdx.x;  // 0..31
  const int ty = threadIdx.y;  // 0..7
#pragma unroll
  for (int i = 0; i < 4; i++) {
    int k = k0 + ty + i * 8;
    tile[ty + i * 8][tx] = src[(size_t)k * srcN + col0 + n0 + tx];
  }
  __syncthreads();
#pragma unroll
  for (int i = 0; i < 4; i++) {
    int n = n0 + ty + i * 8;
    dst[(size_t)n * srcK + k0 + tx] = f2bf(tile[tx][ty + i * 8]);
  }
}

// ---------------------------------------------------------------------------
// LayerNorm: one wave per row of xc[8192][320] -> bf16 xr
// ---------------------------------------------------------------------------
__global__ __launch_bounds__(256)
void k_ln(const float* __restrict__ xc, const float* __restrict__ gam,
          const float* __restrict__ bet, unsigned short* __restrict__ xr) {
  const int row = blockIdx.x * 4 + (threadIdx.x >> 6);
  const int l = threadIdx.x & 63;
  const float* p = xc + (size_t)row * 320;
  float v[5], s = 0.f, ss = 0.f;
#pragma unroll
  for (int i = 0; i < 5; i++) { v[i] = p[l + 64 * i]; s += v[i]; ss += v[i] * v[i]; }
#pragma unroll
  for (int o = 1; o < 64; o <<= 1) { s += __shfl_xor(s, o); ss += __shfl_xor(ss, o); }
  float mu = s * (1.f / 320.f);
  float var = ss * (1.f / 320.f) - mu * mu;
  float rstd = rsqrtf(var + 1e-5f);
  unsigned short* q = xr + (size_t)row * 320;
#pragma unroll
  for (int i = 0; i < 5; i++) {
    int c = l + 64 * i;
    q[c] = f2bf((v[i] - mu) * rstd * gam[c] + bet[c]);
  }
}

// ---------------------------------------------------------------------------
// Generic GEMM: C[M x 320] = A[M x Kdim] * W[Kdim x 320] (+bias), tile 128x64.
// W supplied pre-transposed bf16: Wt[n][k].  2 waves, wave-tile 64x64.
// AKIND: 0 = A fp32 row-major, 1 = A bf16 row-major
// EPI:   0 = Qb bf16 [b][h][4096][64]        (M=32768, bias=q_b)
//        1 = Kb bf16 [b][h][1024][64]        (M=8192,  bias=kv_b)
//        2 = Vt bf16 [b][h][64][1024]        (M=8192,  bias=kv_b+320)
//        3 = out fp32 [M][320]               (M=32768, bias=proj_b)
// ---------------------------------------------------------------------------
template <int AKIND, int EPI>
__global__ __launch_bounds__(128)
void k_gemm(const void* __restrict__ Aptr, const unsigned short* __restrict__ Wt,
            const float* __restrict__ bias, void* __restrict__ outp, int Kdim) {
  __shared__ __align__(16) unsigned char smem[17408];
  unsigned short* Al = (unsigned short*)smem;            // [128][40]
  unsigned short* Bl = (unsigned short*)(smem + 10240);  // [64][40]
  const int t = threadIdx.x;
  const int w = t >> 6, l = t & 63, lr = l & 15, lq = l >> 4;
  const int m0 = blockIdx.x * 128, n0 = blockIdx.y * 64;

  f32x4 acc[4][4];
#pragma unroll
  for (int i = 0; i < 4; i++)
#pragma unroll
    for (int j = 0; j < 4; j++) acc[i][j] = (f32x4){0.f, 0.f, 0.f, 0.f};

  for (int k0 = 0; k0 < Kdim; k0 += 32) {
    if (AKIND == 0) {
      const float* A = (const float*)Aptr;
#pragma unroll
      for (int i = 0; i < 4; i++) {
        int ch = t + 128 * i, r = ch >> 2, g = ch & 3;
        const f32x4* p = (const f32x4*)(A + (size_t)(m0 + r) * Kdim + k0 + g * 8);
        f32x4 v0 = p[0], v1 = p[1];
        bf16x8 o;
        o[0] = (short)f2bf(v0[0]); o[1] = (short)f2bf(v0[1]);
        o[2] = (short)f2bf(v0[2]); o[3] = (short)f2bf(v0[3]);
        o[4] = (short)f2bf(v1[0]); o[5] = (short)f2bf(v1[1]);
        o[6] = (short)f2bf(v1[2]); o[7] = (short)f2bf(v1[3]);
        *(bf16x8*)(Al + r * 40 + g * 8) = o;
      }
    } else {
      const unsigned short* A = (const unsigned short*)Aptr;
#pragma unroll
      for (int i = 0; i < 4; i++) {
        int ch = t + 128 * i, r = ch >> 2, g = ch & 3;
        *(bf16x8*)(Al + r * 40 + g * 8) =
            *(const bf16x8*)(A + (size_t)(m0 + r) * Kdim + k0 + g * 8);
      }
    }
#pragma unroll
    for (int i = 0; i < 2; i++) {
      int ch = t + 128 * i, r = ch >> 2, g = ch & 3;
      *(bf16x8*)(Bl + r * 40 + g * 8) =
          *(const bf16x8*)(Wt + (size_t)(n0 + r) * Kdim + k0 + g * 8);
    }
    __syncthreads();
    bf16x8 af[4], bfr[4];
#pragma unroll
    for (int mi = 0; mi < 4; mi++)
      af[mi] = *(const bf16x8*)(Al + (w * 64 + mi * 16 + lr) * 40 + lq * 8);
#pragma unroll
    for (int ni = 0; ni < 4; ni++)
      bfr[ni] = *(const bf16x8*)(Bl + (ni * 16 + lr) * 40 + lq * 8);
#pragma unroll
    for (int mi = 0; mi < 4; mi++)
#pragma unroll
      for (int ni = 0; ni < 4; ni++)
        acc[mi][ni] =
            __builtin_amdgcn_mfma_f32_16x16x32_bf16(af[mi], bfr[ni], acc[mi][ni], 0, 0, 0);
    __syncthreads();
  }

  if (EPI == 0) {  // Qb [b][h][4096][64]
    unsigned short* out = (unsigned short*)outp;
    const int h = n0 >> 6;
#pragma unroll
    for (int mi = 0; mi < 4; mi++)
#pragma unroll
      for (int ni = 0; ni < 4; ni++)
#pragma unroll
        for (int rr = 0; rr < 4; rr++) {
          int gm = m0 + w * 64 + mi * 16 + lq * 4 + rr;
          int b = gm >> 12, n = gm & 4095, d = ni * 16 + lr;
          out[((size_t)(b * 5 + h) << 18) + ((size_t)n << 6) + d] =
              f2bf(acc[mi][ni][rr] + bias[n0 + d]);
        }
  } else if (EPI == 1) {  // Kb [b][h][1024][64]
    unsigned short* out = (unsigned short*)outp;
    const int h = n0 >> 6;
#pragma unroll
    for (int mi = 0; mi < 4; mi++)
#pragma unroll
      for (int ni = 0; ni < 4; ni++)
#pragma unroll
        for (int rr = 0; rr < 4; rr++) {
          int gm = m0 + w * 64 + mi * 16 + lq * 4 + rr;
          int b = gm >> 10, mm = gm & 1023, d = ni * 16 + lr;
          out[((size_t)(b * 5 + h) << 16) + ((size_t)mm << 6) + d] =
              f2bf(acc[mi][ni][rr] + bias[n0 + d]);
        }
  } else if (EPI == 2) {  // Vt [b][h][64][1024] via LDS bounce
    unsigned short* Tl = (unsigned short*)smem;  // [64][136]
#pragma unroll
    for (int mi = 0; mi < 4; mi++)
#pragma unroll
      for (int ni = 0; ni < 4; ni++)
#pragma unroll
        for (int rr = 0; rr < 4; rr++) {
          int ml = w * 64 + mi * 16 + lq * 4 + rr;  // 0..127
          int d = ni * 16 + lr;
          Tl[d * 136 + ml] = f2bf(acc[mi][ni][rr] + bias[n0 + d]);
        }
    __syncthreads();
    const int b = m0 >> 10, mm0 = m0 & 1023, h = n0 >> 6;
    unsigned short* out = (unsigned short*)outp;
#pragma unroll
    for (int i = 0; i < 8; i++) {
      int ch = t + 128 * i, d = ch >> 4, g = ch & 15;
      *(bf16x8*)(out + ((size_t)(b * 5 + h) << 16) + d * 1024 + mm0 + g * 8) =
          *(const bf16x8*)(Tl + d * 136 + g * 8);
    }
  } else {  // EPI == 3: fp32 out [M][320]
    float* out = (float*)outp;
#pragma unroll
    for (int mi = 0; mi < 4; mi++)
#pragma unroll
      for (int ni = 0; ni < 4; ni++)
#pragma unroll
        for (int rr = 0; rr < 4; rr++) {
          int gm = m0 + w * 64 + mi * 16 + lq * 4 + rr;
          int gc = n0 + ni * 16 + lr;
          out[(size_t)gm * 320 + gc] = acc[mi][ni][rr] + bias[gc];
        }
  }
}

// ---------------------------------------------------------------------------
// SR conv as GEMM: xc[8192][320] = gather(x)[8192][1280] * Wsr[1280][320] + sr_b
// ---------------------------------------------------------------------------
__global__ __launch_bounds__(128)
void k_conv(const float* __restrict__ x, const unsigned short* __restrict__ Wsrt,
            const float* __restrict__ sr_b, float* __restrict__ xc) {
  __shared__ __align__(16) unsigned char smem[15360];
  unsigned short* Al = (unsigned short*)smem;            // [128][40]
  unsigned short* Bl = (unsigned short*)(smem + 10240);  // [64][40]
  const int t = threadIdx.x;
  const int w = t >> 6, l = t & 63, lr = l & 15, lq = l >> 4;
  const int m0 = blockIdx.x * 128, n0 = blockIdx.y * 64;

  f32x4 acc[4][4];
#pragma unroll
  for (int i = 0; i < 4; i++)
#pragma unroll
    for (int j = 0; j < 4; j++) acc[i][j] = (f32x4){0.f, 0.f, 0.f, 0.f};

  for (int k0 = 0; k0 < 1280; k0 += 32) {
    int kh = k0 / 640, rem = k0 - kh * 640, kw = rem / 320, ci0 = rem - kw * 320;
#pragma unroll
    for (int i = 0; i < 4; i++) {
      int ch = t + 128 * i, r = ch >> 2, g = ch & 3;
      int gm = m0 + r, b = gm >> 10, rr2 = gm & 1023, oy = rr2 >> 5, ox = rr2 & 31;
      const float* pp =
          x + (size_t)((b * 64 + 2 * oy + kh) * 64 + 2 * ox + kw) * 320 + ci0 + g * 8;
      f32x4 v0 = ((const f32x4*)pp)[0], v1 = ((const f32x4*)pp)[1];
      bf16x8 o;
      o[0] = (short)f2bf(v0[0]); o[1] = (short)f2bf(v0[1]);
      o[2] = (short)f2bf(v0[2]); o[3] = (short)f2bf(v0[3]);
      o[4] = (short)f2bf(v1[0]); o[5] = (short)f2bf(v1[1]);
      o[6] = (short)f2bf(v1[2]); o[7] = (short)f2bf(v1[3]);
      *(bf16x8*)(Al + r * 40 + g * 8) = o;
    }
#pragma unroll
    for (int i = 0; i < 2; i++) {
      int ch = t + 128 * i, r = ch >> 2, g = ch & 3;
      *(bf16x8*)(Bl + r * 40 + g * 8) =
          *(const bf16x8*)(Wsrt + (size_t)(n0 + r) * 1280 + k0 + g * 8);
    }
    __syncthreads();
    bf16x8 af[4], bfr[4];
#pragma unroll
    for (int mi = 0; mi < 4; mi++)
      af[mi] = *(const bf16x8*)(Al + (w * 64 + mi * 16 + lr) * 40 + lq * 8);
#pragma unroll
    for (int ni = 0; ni < 4; ni++)
      bfr[ni] = *(const bf16x8*)(Bl + (ni * 16 + lr) * 40 + lq * 8);
#pragma unroll
    for (int mi = 0; mi < 4; mi++)
#pragma unroll
      for (int ni = 0; ni < 4; ni++)
        acc[mi][ni] =
            __builtin_amdgcn_mfma_f32_16x16x32_bf16(af[mi], bfr[ni], acc[mi][ni], 0, 0, 0);
    __syncthreads();
  }
#pragma unroll
  for (int mi = 0; mi < 4; mi++)
#pragma unroll
    for (int ni = 0; ni < 4; ni++)
#pragma unroll
      for (int rr = 0; rr < 4; rr++) {
        int gm = m0 + w * 64 + mi * 16 + lq * 4 + rr;
        int gc = n0 + ni * 16 + lr;
        xc[(size_t)gm * 320 + gc] = acc[mi][ni][rr] + sr_b[gc];
      }
}

// ---------------------------------------------------------------------------
// Attention: per (b,h): S = Q*K^T*scale, P = exp(S), O = (P V) / rowsum(P).
// Block: 256 thr = 4 waves; wave = 32 q rows; KV chunk = 64. No running max
// (logits are O(1); exp-sum in fp32 is safe).
// ---------------------------------------------------------------------------
__global__ __launch_bounds__(256)
void k_attn(const unsigned short* __restrict__ Qb, const unsigned short* __restrict__ Kb,
            const unsigned short* __restrict__ Vt, unsigned short* __restrict__ AO) {
  __shared__ __align__(16) unsigned char smem[36864];
  unsigned short* Kl = (unsigned short*)smem;           // [64][72]
  unsigned short* Vl = (unsigned short*)(smem + 9216);  // [64][72] (d-major)
  const int t = threadIdx.x, w = t >> 6, l = t & 63, lr = l & 15, lq = l >> 4;
  unsigned short* Pl = (unsigned short*)(smem + 18432) + w * (32 * 72);  // [32][72]
  const int bh = blockIdx.y;
  const int m0 = blockIdx.x * 128 + w * 32;
  const unsigned short* Qp = Qb + ((size_t)bh << 18);
  const unsigned short* Kp = Kb + ((size_t)bh << 16);
  const unsigned short* Vp = Vt + ((size_t)bh << 16);

  bf16x8 qf[2][2];
#pragma unroll
  for (int mi = 0; mi < 2; mi++)
#pragma unroll
    for (int tt = 0; tt < 2; tt++)
      qf[mi][tt] = *(const bf16x8*)(Qp + (size_t)(m0 + mi * 16 + lr) * 64 + tt * 32 + lq * 8);

  f32x4 oacc[2][4];
  float den[2][4];
#pragma unroll
  for (int mi = 0; mi < 2; mi++)
#pragma unroll
    for (int j = 0; j < 4; j++) {
      oacc[mi][j] = (f32x4){0.f, 0.f, 0.f, 0.f};
      den[mi][j] = 0.f;
    }

  const float S2 = 0.125f * 1.4426950408889634f;  // scale * log2(e)

  for (int c = 0; c < 16; c++) {
    __syncthreads();
#pragma unroll
    for (int i = 0; i < 2; i++) {
      int ch = t + 256 * i, r = ch >> 3, g = ch & 7;
      *(bf16x8*)(Kl + r * 72 + g * 8) = *(const bf16x8*)(Kp + (size_t)(c * 64 + r) * 64 + g * 8);
      *(bf16x8*)(Vl + r * 72 + g * 8) = *(const bf16x8*)(Vp + (size_t)r * 1024 + c * 64 + g * 8);
    }
    __syncthreads();

    f32x4 sacc[2][4];
#pragma unroll
    for (int mi = 0; mi < 2; mi++)
#pragma unroll
      for (int ni = 0; ni < 4; ni++) sacc[mi][ni] = (f32x4){0.f, 0.f, 0.f, 0.f};
#pragma unroll
    for (int ni = 0; ni < 4; ni++) {
      bf16x8 kf0 = *(const bf16x8*)(Kl + (ni * 16 + lr) * 72 + lq * 8);
      bf16x8 kf1 = *(const bf16x8*)(Kl + (ni * 16 + lr) * 72 + 32 + lq * 8);
#pragma unroll
      for (int mi = 0; mi < 2; mi++) {
        sacc[mi][ni] = __builtin_amdgcn_mfma_f32_16x16x32_bf16(qf[mi][0], kf0, sacc[mi][ni], 0, 0, 0);
        sacc[mi][ni] = __builtin_amdgcn_mfma_f32_16x16x32_bf16(qf[mi][1], kf1, sacc[mi][ni], 0, 0, 0);
      }
    }
#pragma unroll
    for (int mi = 0; mi < 2; mi++)
#pragma unroll
      for (int ni = 0; ni < 4; ni++)
#pragma unroll
        for (int rr = 0; rr < 4; rr++) {
          float p = fast_exp2(sacc[mi][ni][rr] * S2);
          den[mi][rr] += p;
          Pl[(mi * 16 + lq * 4 + rr) * 72 + ni * 16 + lr] = f2bf(p);
        }
    __syncthreads();
#pragma unroll
    for (int tt = 0; tt < 2; tt++) {
      bf16x8 pf[2];
#pragma unroll
      for (int mi = 0; mi < 2; mi++)
        pf[mi] = *(const bf16x8*)(Pl + (mi * 16 + lr) * 72 + tt * 32 + lq * 8);
#pragma unroll
      for (int ni = 0; ni < 4; ni++) {
        bf16x8 vf = *(const bf16x8*)(Vl + (ni * 16 + lr) * 72 + tt * 32 + lq * 8);
#pragma unroll
        for (int mi = 0; mi < 2; mi++)
          oacc[mi][ni] = __builtin_amdgcn_mfma_f32_16x16x32_bf16(pf[mi], vf, oacc[mi][ni], 0, 0, 0);
      }
    }
  }

#pragma unroll
  for (int mi = 0; mi < 2; mi++)
#pragma unroll
    for (int rr = 0; rr < 4; rr++) {
      float d = den[mi][rr];
      d += __shfl_xor(d, 1); d += __shfl_xor(d, 2);
      d += __shfl_xor(d, 4); d += __shfl_xor(d, 8);
      den[mi][rr] = 1.f / d;
    }
  const int b = bh / 5, h = bh - b * 5;
#pragma unroll
  for (int mi = 0; mi < 2; mi++)
#pragma unroll
    for (int ni = 0; ni < 4; ni++)
#pragma unroll
      for (int rr = 0; rr < 4; rr++) {
        int n = m0 + mi * 16 + lq * 4 + rr;
        int col = h * 64 + ni * 16 + lr;
        AO[(size_t)(b * 4096 + n) * 320 + col] = f2bf(oacc[mi][ni][rr] * den[mi][rr]);
      }
}

// ---------------------------------------------------------------------------
extern "C" void kernel_launch(void* const* d_in, const int* in_sizes, int n_in,
                              void* d_out, int out_size, void* d_ws, size_t ws_size,
                              hipStream_t stream) {
  (void)in_sizes; (void)n_in; (void)out_size; (void)ws_size;
  const float* x      = (const float*)d_in[0];
  const float* q_w    = (const float*)d_in[1];
  const float* q_b    = (const float*)d_in[2];
  const float* kv_w   = (const float*)d_in[3];
  const float* kv_b   = (const float*)d_in[4];
  const float* sr_w   = (const float*)d_in[5];
  const float* sr_b   = (const float*)d_in[6];
  const float* ln_g   = (const float*)d_in[7];
  const float* ln_b   = (const float*)d_in[8];
  const float* proj_w = (const float*)d_in[9];
  const float* proj_b = (const float*)d_in[10];
  float* out = (float*)d_out;

  char* ws = (char*)d_ws;
  size_t off = 0;
  auto alloc = [&](size_t bytes) {
    void* p = ws + off;
    off += (bytes + 255) & ~(size_t)255;
    return p;
  };
  unsigned short* Qb   = (unsigned short*)alloc((size_t)32768 * 320 * 2);
  unsigned short* KbP  = (unsigned short*)alloc((size_t)40 * 65536 * 2);
  unsigned short* VtP  = (unsigned short*)alloc((size_t)40 * 65536 * 2);
  float*          xc   = (float*)alloc((size_t)8192 * 320 * 4);
  unsigned short* xr   = (unsigned short*)alloc((size_t)8192 * 320 * 2);
  unsigned short* AO   = (unsigned short*)alloc((size_t)32768 * 320 * 2);
  unsigned short* Wq_t = (unsigned short*)alloc((size_t)320 * 320 * 2);
  unsigned short* Wk_t = (unsigned short*)alloc((size_t)320 * 320 * 2);
  unsigned short* Wv_t = (unsigned short*)alloc((size_t)320 * 320 * 2);
  unsigned short* Wp_t = (unsigned short*)alloc((size_t)320 * 320 * 2);
  unsigned short* Wsr_t= (unsigned short*)alloc((size_t)320 * 1280 * 2);

  dim3 tb(32, 8);
  k_transpose<<<dim3(10, 10), tb, 0, stream>>>(q_w,    320,  320,   0, Wq_t);
  k_transpose<<<dim3(10, 10), tb, 0, stream>>>(kv_w,   320,  640,   0, Wk_t);
  k_transpose<<<dim3(10, 10), tb, 0, stream>>>(kv_w,   320,  640, 320, Wv_t);
  k_transpose<<<dim3(10, 10), tb, 0, stream>>>(proj_w, 320,  320,   0, Wp_t);
  k_transpose<<<dim3(40, 10), tb, 0, stream>>>(sr_w,  1280,  320,   0, Wsr_t);

  k_conv<<<dim3(64, 5), 128, 0, stream>>>(x, Wsr_t, sr_b, xc);
  k_ln<<<2048, 256, 0, stream>>>(xc, ln_g, ln_b, xr);
  k_gemm<0, 0><<<dim3(256, 5), 128, 0, stream>>>(x,  Wq_t, q_b,       Qb,  320);
  k_gemm<1, 1><<<dim3(64, 5),  128, 0, stream>>>(xr, Wk_t, kv_b,      KbP, 320);
  k_gemm<1, 2><<<dim3(64, 5),  128, 0, stream>>>(xr, Wv_t, kv_b + 320, VtP, 320);
  k_attn<<<dim3(32, 40), 256, 0, stream>>>(Qb, KbP, VtP, AO);
  k_gemm<1, 3><<<dim3(256, 5), 128, 0, stream>>>(AO, Wp_t, proj_b, out, 320);
}

// Round 2
// 270.421 us; speedup vs baseline: 1.1670x; 1.1670x over previous
//
#include <hip/hip_runtime.h>

typedef __attribute__((ext_vector_type(8))) short bf16x8;
typedef __attribute__((ext_vector_type(4))) short bf16x4;
typedef __attribute__((ext_vector_type(4))) float f32x4;
typedef __attribute__((ext_vector_type(2))) unsigned u32x2;

#define DEVI static __device__ __forceinline__
#define AS1 __attribute__((address_space(1)))
#define AS3 __attribute__((address_space(3)))

DEVI unsigned short f2bf(float f) {
  unsigned u = __builtin_bit_cast(unsigned, f);
  return (unsigned short)((u + 0x7FFFu + ((u >> 16) & 1u)) >> 16);
}

DEVI unsigned pkbf(float a, float b) {
  return (unsigned)f2bf(a) | ((unsigned)f2bf(b) << 16);
}

DEVI float fast_exp2(float x) {
#if __has_builtin(__builtin_amdgcn_exp2f)
  return __builtin_amdgcn_exp2f(x);
#else
  return exp2f(x);
#endif
}

// async 16B global->LDS; LDS dest = uniform base + lane*16
DEVI void gl_lds16(const unsigned short* g, unsigned short* l) {
  __builtin_amdgcn_global_load_lds((const AS1 unsigned int*)g, (AS3 unsigned int*)l, 16, 0, 0);
}

// PV mfma: D = A(4 bf16) * B(4 bf16) + C, 16x16x16
DEVI f32x4 pv_mfma(bf16x4 a, bf16x4 b, f32x4 c) {
#if __has_builtin(__builtin_amdgcn_mfma_f32_16x16x16bf16_1k)
  return __builtin_amdgcn_mfma_f32_16x16x16bf16_1k(a, b, c, 0, 0, 0);
#elif __has_builtin(__builtin_amdgcn_mfma_f32_16x16x16_bf16)
  return __builtin_amdgcn_mfma_f32_16x16x16_bf16(a, b, c, 0, 0, 0);
#else
  bf16x8 a8 = {a[0], a[1], a[2], a[3], (short)0, (short)0, (short)0, (short)0};
  bf16x8 b8 = {b[0], b[1], b[2], b[3], (short)0, (short)0, (short)0, (short)0};
  return __builtin_amdgcn_mfma_f32_16x16x32_bf16(a8, b8, c, 0, 0, 0);
#endif
}

// ---------------------------------------------------------------------------
// x fp32 -> bf16 (10,485,760 elems)
// ---------------------------------------------------------------------------
__global__ __launch_bounds__(256)
void k_prep(const float* __restrict__ x, unsigned short* __restrict__ xb) {
  size_t i = ((size_t)blockIdx.x * 256 + threadIdx.x) * 8;
  const size_t stride = (size_t)gridDim.x * 256 * 8;
  for (; i < (size_t)10485760; i += stride) {
    f32x4 a = *(const f32x4*)(x + i), b = *(const f32x4*)(x + i + 4);
    bf16x8 o;
    o[0] = (short)f2bf(a[0]); o[1] = (short)f2bf(a[1]);
    o[2] = (short)f2bf(a[2]); o[3] = (short)f2bf(a[3]);
    o[4] = (short)f2bf(b[0]); o[5] = (short)f2bf(b[1]);
    o[6] = (short)f2bf(b[2]); o[7] = (short)f2bf(b[3]);
    *(bf16x8*)(xb + i) = o;
  }
}

// ---------------------------------------------------------------------------
// All weight transposes in one launch. fp32 src[K][N] -> bf16 dst[N][K]
// z=0: q_w 320x320  z=1: kv_w 320x640  z=2: proj_w 320x320  z=3: sr_w 1280x320
// ---------------------------------------------------------------------------
__global__ __launch_bounds__(256)
void k_transpose_all(const float* __restrict__ q_w, const float* __restrict__ kv_w,
                     const float* __restrict__ proj_w, const float* __restrict__ sr_w,
                     unsigned short* __restrict__ Wq, unsigned short* __restrict__ Wkv,
                     unsigned short* __restrict__ Wp, unsigned short* __restrict__ Wsr) {
  const float* src; unsigned short* dst; int K, N;
  switch (blockIdx.z) {
    case 0:  src = q_w;    dst = Wq;  K = 320;  N = 320; break;
    case 1:  src = kv_w;   dst = Wkv; K = 320;  N = 640; break;
    case 2:  src = proj_w; dst = Wp;  K = 320;  N = 320; break;
    default: src = sr_w;   dst = Wsr; K = 1280; N = 320; break;
  }
  if ((int)blockIdx.x >= (K >> 5) || (int)blockIdx.y >= (N >> 5)) return;
  __shared__ float tile[32][33];
  const int k0 = blockIdx.x * 32, n0 = blockIdx.y * 32;
  const int tx = threadIdx.x, ty = threadIdx.y;
#pragma unroll
  for (int i = 0; i < 4; i++)
    tile[ty + i * 8][tx] = src[(size_t)(k0 + ty + i * 8) * N + n0 + tx];
  __syncthreads();
#pragma unroll
  for (int i = 0; i < 4; i++)
    dst[(size_t)(n0 + ty + i * 8) * K + k0 + tx] = f2bf(tile[tx][ty + i * 8]);
}

// ---------------------------------------------------------------------------
// LayerNorm: one wave per row of xc[8192][320] -> bf16 xr
// ---------------------------------------------------------------------------
__global__ __launch_bounds__(256)
void k_ln(const float* __restrict__ xc, const float* __restrict__ gam,
          const float* __restrict__ bet, unsigned short* __restrict__ xr) {
  const int row = blockIdx.x * 4 + (threadIdx.x >> 6);
  const int l = threadIdx.x & 63;
  const float* p = xc + (size_t)row * 320;
  float v[5], s = 0.f, ss = 0.f;
#pragma unroll
  for (int i = 0; i < 5; i++) { v[i] = p[l + 64 * i]; s += v[i]; ss += v[i] * v[i]; }
#pragma unroll
  for (int o = 1; o < 64; o <<= 1) { s += __shfl_xor(s, o); ss += __shfl_xor(ss, o); }
  float mu = s * (1.f / 320.f);
  float var = ss * (1.f / 320.f) - mu * mu;
  float rstd = rsqrtf(var + 1e-5f);
  unsigned short* q = xr + (size_t)row * 320;
#pragma unroll
  for (int i = 0; i < 5; i++) {
    int c = l + 64 * i;
    q[c] = f2bf((v[i] - mu) * rstd * gam[c] + bet[c]);
  }
}

// ---------------------------------------------------------------------------
// GEMM: C[M x 320-slice] = A[M x Kdim] * Wt^T (+bias), tile 128x64, BK=32.
// A and B staged via global_load_lds(16B) with source-side XOR swizzle
// (granule g stored at slot g ^ ((row>>1)&3); 2-way bank aliasing = free).
// AKIND: 0 = A bf16 row-major;  2 = SR-conv gather from bf16 x image
// EPI:   0 = Qb bf16 [b][h][4096][64] *oscale   1 = Kb bf16 [b][h][1024][64]
//        2 = Vt bf16 [b][h][64][1024]           3 = fp32 out [M][320]
// ---------------------------------------------------------------------------
template <int AKIND, int EPI>
__global__ __launch_bounds__(128)
void k_gemm(const unsigned short* __restrict__ A, const unsigned short* __restrict__ Wt,
            const float* __restrict__ bias, void* __restrict__ outp, int Kdim, float oscale) {
  __shared__ __align__(16) unsigned char smem[17408];  // A 8192 + B 4096 (EPI2 bounce 17408)
  unsigned short* Al = (unsigned short*)smem;
  unsigned short* Bl = (unsigned short*)(smem + 8192);
  const int t = threadIdx.x, w = t >> 6, ln = t & 63, lr = ln & 15, lq = ln >> 4;
  const int m0 = blockIdx.x * 128, n0 = blockIdx.y * 64;
  const int sA = ln & 3, rA = ln >> 2;

  f32x4 acc[4][4];
#pragma unroll
  for (int i = 0; i < 4; i++)
#pragma unroll
    for (int j = 0; j < 4; j++) acc[i][j] = (f32x4){0.f, 0.f, 0.f, 0.f};

  // per-thread constant staging descriptors
  int rowA[4], gA[4], rowB[2], gB[2];
#pragma unroll
  for (int i = 0; i < 4; i++) {
    rowA[i] = (w * 4 + i) * 16 + rA;
    gA[i] = sA ^ ((rowA[i] >> 1) & 3);
  }
#pragma unroll
  for (int i = 0; i < 2; i++) {
    rowB[i] = (w * 2 + i) * 16 + rA;
    gB[i] = sA ^ ((rowB[i] >> 1) & 3);
  }

  int kh = 0, kw = 0, ci0 = 0;  // conv k-block decomposition (uniform)
  for (int k0 = 0; k0 < Kdim; k0 += 32) {
    if (AKIND == 0) {
#pragma unroll
      for (int i = 0; i < 4; i++)
        gl_lds16(A + (size_t)(m0 + rowA[i]) * Kdim + k0 + gA[i] * 8,
                 Al + (w * 4 + i) * 512);
    } else {  // conv gather: row -> output pixel, k-block within one (kh,kw)
#pragma unroll
      for (int i = 0; i < 4; i++) {
        int gm = m0 + rowA[i];
        int b = gm >> 10, pix = gm & 1023, oy = pix >> 5, ox = pix & 31;
        gl_lds16(A + (size_t)((b * 64 + 2 * oy + kh) * 64 + 2 * ox + kw) * 320 + ci0 + gA[i] * 8,
                 Al + (w * 4 + i) * 512);
      }
    }
#pragma unroll
    for (int i = 0; i < 2; i++)
      gl_lds16(Wt + (size_t)(n0 + rowB[i]) * Kdim + k0 + gB[i] * 8,
               Bl + (w * 2 + i) * 512);
    if (AKIND == 2) {  // advance (kh,kw,ci0)
      ci0 += 32;
      if (ci0 == 320) { ci0 = 0; kw++; if (kw == 2) { kw = 0; kh++; } }
    }
    __syncthreads();
    bf16x8 af[4], bfr[4];
#pragma unroll
    for (int mi = 0; mi < 4; mi++) {
      int ra = w * 64 + mi * 16 + lr;
      af[mi] = *(const bf16x8*)(Al + ra * 32 + (lq ^ ((ra >> 1) & 3)) * 8);
    }
#pragma unroll
    for (int ni = 0; ni < 4; ni++) {
      int rb = ni * 16 + lr;
      bfr[ni] = *(const bf16x8*)(Bl + rb * 32 + (lq ^ ((rb >> 1) & 3)) * 8);
    }
#pragma unroll
    for (int mi = 0; mi < 4; mi++)
#pragma unroll
      for (int ni = 0; ni < 4; ni++)
        acc[mi][ni] =
            __builtin_amdgcn_mfma_f32_16x16x32_bf16(af[mi], bfr[ni], acc[mi][ni], 0, 0, 0);
    __syncthreads();
  }

  if (EPI == 0) {  // Qb [b][h][4096][64], scaled
    unsigned short* out = (unsigned short*)outp;
    const int h = n0 >> 6;
#pragma unroll
    for (int mi = 0; mi < 4; mi++)
#pragma unroll
      for (int ni = 0; ni < 4; ni++)
#pragma unroll
        for (int rr = 0; rr < 4; rr++) {
          int gm = m0 + w * 64 + mi * 16 + lq * 4 + rr;
          int b = gm >> 12, n = gm & 4095, d = ni * 16 + lr;
          out[((size_t)(b * 5 + h) << 18) + ((size_t)n << 6) + d] =
              f2bf((acc[mi][ni][rr] + bias[n0 + d]) * oscale);
        }
  } else if (EPI == 1) {  // Kb [b][h][1024][64]
    unsigned short* out = (unsigned short*)outp;
    const int h = n0 >> 6;
#pragma unroll
    for (int mi = 0; mi < 4; mi++)
#pragma unroll
      for (int ni = 0; ni < 4; ni++)
#pragma unroll
        for (int rr = 0; rr < 4; rr++) {
          int gm = m0 + w * 64 + mi * 16 + lq * 4 + rr;
          int b = gm >> 10, mm = gm & 1023, d = ni * 16 + lr;
          out[((size_t)(b * 5 + h) << 16) + ((size_t)mm << 6) + d] =
              f2bf(acc[mi][ni][rr] + bias[n0 + d]);
        }
  } else if (EPI == 2) {  // Vt [b][h][64][1024] via LDS bounce
    unsigned short* Tl = (unsigned short*)smem;  // [64][136]
    __syncthreads();
#pragma unroll
    for (int mi = 0; mi < 4; mi++)
#pragma unroll
      for (int ni = 0; ni < 4; ni++)
#pragma unroll
        for (int rr = 0; rr < 4; rr++) {
          int ml = w * 64 + mi * 16 + lq * 4 + rr;
          int d = ni * 16 + lr;
          Tl[d * 136 + ml] = f2bf(acc[mi][ni][rr] + bias[n0 + d]);
        }
    __syncthreads();
    const int b = m0 >> 10, mm0 = m0 & 1023, h = n0 >> 6;
    unsigned short* out = (unsigned short*)outp;
#pragma unroll
    for (int i = 0; i < 8; i++) {
      int ch = t + 128 * i, d = ch >> 4, g = ch & 15;
      *(bf16x8*)(out + ((size_t)(b * 5 + h) << 16) + d * 1024 + mm0 + g * 8) =
          *(const bf16x8*)(Tl + d * 136 + g * 8);
    }
  } else {  // fp32 [M][320]
    float* out = (float*)outp;
#pragma unroll
    for (int mi = 0; mi < 4; mi++)
#pragma unroll
      for (int ni = 0; ni < 4; ni++)
#pragma unroll
        for (int rr = 0; rr < 4; rr++) {
          int gm = m0 + w * 64 + mi * 16 + lq * 4 + rr;
          int gc = n0 + ni * 16 + lr;
          out[(size_t)gm * 320 + gc] = acc[mi][ni][rr] + bias[gc];
        }
  }
}

// ---------------------------------------------------------------------------
// Attention. Per (b,h): S^T = K*Q^T (so P^T lands in the B-operand layout of
// mfma_16x16x16), chain P^T straight from registers into PV: O^T = V^T * P^T.
// Wave = 32 q-rows, chunk = 64 kv. K/V staged via global_load_lds w/ swizzle.
// Q is pre-scaled by SCALE*log2(e) so p = exp2(s) directly.
// ---------------------------------------------------------------------------
__global__ __launch_bounds__(256)
void k_attn(const unsigned short* __restrict__ Qb, const unsigned short* __restrict__ Kb,
            const unsigned short* __restrict__ Vt, unsigned short* __restrict__ AO) {
  __shared__ __align__(16) unsigned char smem[16384];
  unsigned short* KL = (unsigned short*)smem;        // [64 kv][8 gran of 8 bf16] swizzled
  unsigned short* VL = KL + 4096;                    // [64 d][8 gran over kv] swizzled
  const int t = threadIdx.x, w = t >> 6, ln = t & 63, lr = ln & 15, lq = ln >> 4;
  const int bh = blockIdx.y;
  const int m0 = blockIdx.x * 128 + w * 32;
  const unsigned short* Qp = Qb + ((size_t)bh << 18);
  const unsigned short* Kp = Kb + ((size_t)bh << 16);
  const unsigned short* Vp = Vt + ((size_t)bh << 16);

  // Q fragments (row-major A-layout, doubles as B-operand of S^T = K*Q^T)
  bf16x8 qf[2][2];
#pragma unroll
  for (int mt = 0; mt < 2; mt++)
#pragma unroll
    for (int t2 = 0; t2 < 2; t2++)
      qf[mt][t2] = *(const bf16x8*)(Qp + (size_t)(m0 + mt * 16 + lr) * 64 + t2 * 32 + lq * 8);

  f32x4 oacc[4][2];  // [dtile][mtile]
  float den[2] = {0.f, 0.f};
#pragma unroll
  for (int dt = 0; dt < 4; dt++)
#pragma unroll
    for (int mt = 0; mt < 2; mt++) oacc[dt][mt] = (f32x4){0.f, 0.f, 0.f, 0.f};

  // staging descriptors (constant per thread)
  const int rS = (ln >> 3);      // row-local within an 8-row instruction
  const int sS = ln & 7;         // slot

  for (int c = 0; c < 16; c++) {
#pragma unroll
    for (int i = 0; i < 2; i++) {
      int r = (w * 2 + i) * 8 + rS;
      int g = sS ^ (r & 7);
      gl_lds16(Kp + (size_t)(c * 64 + r) * 64 + g * 8, KL + (w * 2 + i) * 512);
      gl_lds16(Vp + (size_t)r * 1024 + c * 64 + g * 8, VL + (w * 2 + i) * 512);
    }
    __syncthreads();

    // S^T[kv 64][m 32]
    f32x4 sacc[4][2];
#pragma unroll
    for (int kt = 0; kt < 4; kt++) {
      int kr = 16 * kt + lr;
      bf16x8 kf0 = *(const bf16x8*)(KL + kr * 64 + ((lq ^ (lr & 7)) * 8));
      bf16x8 kf1 = *(const bf16x8*)(KL + kr * 64 + (((4 + lq) ^ (lr & 7)) * 8));
#pragma unroll
      for (int mt = 0; mt < 2; mt++) {
        f32x4 s = (f32x4){0.f, 0.f, 0.f, 0.f};
        s = __builtin_amdgcn_mfma_f32_16x16x32_bf16(kf0, qf[mt][0], s, 0, 0, 0);
        s = __builtin_amdgcn_mfma_f32_16x16x32_bf16(kf1, qf[mt][1], s, 0, 0, 0);
        sacc[kt][mt] = s;
      }
    }

    // exp + pack P^T (already B-layout for 16x16x16)
    bf16x4 pf[4][2];
#pragma unroll
    for (int kt = 0; kt < 4; kt++)
#pragma unroll
      for (int mt = 0; mt < 2; mt++) {
        float p0 = fast_exp2(sacc[kt][mt][0]);
        float p1 = fast_exp2(sacc[kt][mt][1]);
        float p2 = fast_exp2(sacc[kt][mt][2]);
        float p3 = fast_exp2(sacc[kt][mt][3]);
        den[mt] += (p0 + p1) + (p2 + p3);
        u32x2 pk = {pkbf(p0, p1), pkbf(p2, p3)};
        pf[kt][mt] = __builtin_bit_cast(bf16x4, pk);
      }

    // O^T += V^T * P^T
#pragma unroll
    for (int kt = 0; kt < 4; kt++)
#pragma unroll
      for (int dt = 0; dt < 4; dt++) {
        int vr = 16 * dt + lr;
        bf16x4 vf = *(const bf16x4*)(VL + vr * 64 + ((2 * kt + (lq >> 1)) ^ (lr & 7)) * 8 +
                                     (lq & 1) * 4);
#pragma unroll
        for (int mt = 0; mt < 2; mt++)
          oacc[dt][mt] = pv_mfma(vf, pf[kt][mt], oacc[dt][mt]);
      }
    __syncthreads();
  }

  // reduce denominators across the 4 lane-quads (columns m=lr identical)
  float inv[2];
#pragma unroll
  for (int mt = 0; mt < 2; mt++) {
    float s = den[mt];
    s += __shfl_xor(s, 16);
    s += __shfl_xor(s, 32);
    inv[mt] = 1.f / s;
  }

  const int b = bh / 5, h = bh - b * 5;
#pragma unroll
  for (int mt = 0; mt < 2; mt++)
#pragma unroll
    for (int dt = 0; dt < 4; dt++) {
      float i0 = inv[mt];
      u32x2 pk = {pkbf(oacc[dt][mt][0] * i0, oacc[dt][mt][1] * i0),
                  pkbf(oacc[dt][mt][2] * i0, oacc[dt][mt][3] * i0)};
      int n = m0 + mt * 16 + lr;
      *(u32x2*)(AO + (size_t)(b * 4096 + n) * 320 + h * 64 + dt * 16 + lq * 4) = pk;
    }
}

// ---------------------------------------------------------------------------
extern "C" void kernel_launch(void* const* d_in, const int* in_sizes, int n_in,
                              void* d_out, int out_size, void* d_ws, size_t ws_size,
                              hipStream_t stream) {
  (void)in_sizes; (void)n_in; (void)out_size; (void)ws_size;
  const float* x      = (const float*)d_in[0];
  const float* q_w    = (const float*)d_in[1];
  const float* q_b    = (const float*)d_in[2];
  const float* kv_w   = (const float*)d_in[3];
  const float* kv_b   = (const float*)d_in[4];
  const float* sr_w   = (const float*)d_in[5];
  const float* sr_b   = (const float*)d_in[6];
  const float* ln_g   = (const float*)d_in[7];
  const float* ln_b   = (const float*)d_in[8];
  const float* proj_w = (const float*)d_in[9];
  const float* proj_b = (const float*)d_in[10];
  float* out = (float*)d_out;

  char* ws = (char*)d_ws;
  size_t off = 0;
  auto alloc = [&](size_t bytes) {
    void* p = ws + off;
    off += (bytes + 255) & ~(size_t)255;
    return p;
  };
  unsigned short* xbf  = (unsigned short*)alloc((size_t)32768 * 320 * 2);  // aliased by AO
  unsigned short* Qb   = (unsigned short*)alloc((size_t)32768 * 320 * 2);
  unsigned short* KbP  = (unsigned short*)alloc((size_t)40 * 65536 * 2);
  unsigned short* VtP  = (unsigned short*)alloc((size_t)40 * 65536 * 2);
  float*          xc   = (float*)alloc((size_t)8192 * 320 * 4);
  unsigned short* xr   = (unsigned short*)alloc((size_t)8192 * 320 * 2);
  unsigned short* Wq_t = (unsigned short*)alloc((size_t)320 * 320 * 2);
  unsigned short* Wkv_t= (unsigned short*)alloc((size_t)640 * 320 * 2);
  unsigned short* Wp_t = (unsigned short*)alloc((size_t)320 * 320 * 2);
  unsigned short* Wsr_t= (unsigned short*)alloc((size_t)320 * 1280 * 2);
  unsigned short* AO = xbf;  // x (bf16) is dead once Q projection has run

  const float S2 = 0.125f * 1.4426950408889634f;  // SCALE * log2(e)

  k_prep<<<1280, 256, 0, stream>>>(x, xbf);
  k_transpose_all<<<dim3(40, 20, 4), dim3(32, 8), 0, stream>>>(
      q_w, kv_w, proj_w, sr_w, Wq_t, Wkv_t, Wp_t, Wsr_t);

  k_gemm<2, 3><<<dim3(64, 5), 128, 0, stream>>>(xbf, Wsr_t, sr_b, xc, 1280, 1.f);  // SR conv
  k_ln<<<2048, 256, 0, stream>>>(xc, ln_g, ln_b, xr);
  k_gemm<0, 0><<<dim3(256, 5), 128, 0, stream>>>(xbf, Wq_t, q_b, Qb, 320, S2);
  k_gemm<0, 1><<<dim3(64, 5), 128, 0, stream>>>(xr, Wkv_t, kv_b, KbP, 320, 1.f);
  k_gemm<0, 2><<<dim3(64, 5), 128, 0, stream>>>(xr, Wkv_t + (size_t)320 * 320, kv_b + 320,
                                                VtP, 320, 1.f);
  k_attn<<<dim3(32, 40), 256, 0, stream>>>(Qb, KbP, VtP, AO);
  k_gemm<0, 3><<<dim3(256, 5), 128, 0, stream>>>(AO, Wp_t, proj_b, out, 320, 1.f);
}